// Round 9
// baseline (218.422 us; speedup 1.0000x reference)
//
#include <hip/hip_runtime.h>
#include <stdint.h>

typedef short bf16x8 __attribute__((ext_vector_type(8)));
typedef float f32x4 __attribute__((ext_vector_type(4)));

__device__ __forceinline__ unsigned short f2bf(float f) {
  uint32_t u = __float_as_uint(f);
  u = (u + 0x7FFFu + ((u >> 16) & 1u)) >> 16;
  return (unsigned short)u;
}
__device__ __forceinline__ float bf2f(unsigned short h) {
  return __uint_as_float(((uint32_t)h) << 16);
}

__device__ __forceinline__ void gload16(const void* g, void* lds) {
  const __attribute__((address_space(1))) char* gp =
      (const __attribute__((address_space(1))) char*)(uintptr_t)g;
  __attribute__((address_space(3))) char* sp =
      (__attribute__((address_space(3))) char*)(uint32_t)(uintptr_t)lds;
  __builtin_amdgcn_global_load_lds(gp, sp, 16, 0, 0);
}

// ---------------- fused fp32 -> bf16 converts (all 5 tensors, one dispatch) ----------------
__global__ void k_cvt_all(const float* __restrict__ x, const float* __restrict__ Wq,
                          const float* __restrict__ Wk, const float* __restrict__ Wv,
                          const float* __restrict__ Wo, unsigned short* __restrict__ xb,
                          unsigned short* __restrict__ Wcat, unsigned short* __restrict__ Wob) {
  int b = blockIdx.x;
  const float* src;
  unsigned short* dst;
  int off;
  if (b < 4096)       { src = x;  dst = xb;                  off = b; }
  else if (b < 8192)  { src = Wq; dst = Wcat;                off = b - 4096; }
  else if (b < 9216)  { src = Wk; dst = Wcat + 2048 * 2048;  off = b - 8192; }
  else if (b < 10240) { src = Wv; dst = Wcat + 2560 * 2048;  off = b - 9216; }
  else                { src = Wo; dst = Wob;                  off = b - 10240; }
  int i = off * 256 + threadIdx.x;
  float4 v = ((const float4*)src)[i];
  ushort4 o;
  o.x = f2bf(v.x); o.y = f2bf(v.y); o.z = f2bf(v.z); o.w = f2bf(v.w);
  ((ushort4*)dst)[i] = o;
}

// ---------------- bf16 GEMM, double-buffered: C[m][n] = sum_k A[m][k]*B[n][k] --------------
template <int OUTF32>
__global__ __launch_bounds__(256) void k_gemm(const unsigned short* __restrict__ A,
                                              const unsigned short* __restrict__ B,
                                              void* __restrict__ Cout,
                                              int M, int N, int K) {
  __shared__ unsigned short As[2][128 * 64];
  __shared__ unsigned short Bs[2][128 * 64];
  const int tid = threadIdx.x;
  const int w = tid >> 6, lane = tid & 63;
  const int g = lane >> 4, cl = lane & 15;
  const int nTn = N >> 7;
  // XCD-aware bijective swizzle (gridDim.x % 8 == 0 for both call sites)
  const int per = gridDim.x >> 3;
  const int bid = (blockIdx.x & 7) * per + (blockIdx.x >> 3);
  const int tm = bid / nTn, tn = bid % nTn;
  const int m0 = tm << 7, n0 = tn << 7;
  const int wm = (w >> 1) << 6, wn = (w & 1) << 6;
  f32x4 acc[4][4] = {};

  auto stage = [&](int kt, int b) {
#pragma unroll
    for (int it = 0; it < 8; ++it) {
      int cc = tid + it * 256;          // 2048 16B chunks (As 1024 + Bs 1024)
      int half = cc >> 10;
      int c3 = cc & 1023;
      int row = c3 >> 3, kb = (c3 & 7) << 4;
      const unsigned short* base = half ? (B + (size_t)(n0 + row) * K + kt)
                                        : (A + (size_t)(m0 + row) * K + kt);
      const char* src = (const char*)base + (kb ^ ((row & 7) << 4));
      char* dstl = (char*)(half ? Bs[b] : As[b]) + c3 * 16;
      gload16(src, dstl);
    }
  };

  stage(0, 0);
  asm volatile("s_waitcnt vmcnt(0)" ::: "memory");
  __syncthreads();
  int buf = 0;

  for (int kt = 0; kt < K; kt += 64) {
    if (kt + 64 < K) stage(kt + 64, buf ^ 1);  // prefetch next K-tile, lands during compute
#pragma unroll
    for (int ks = 0; ks < 2; ++ks) {
      bf16x8 af[4], bfr[4];
#pragma unroll
      for (int i = 0; i < 4; ++i) {
        int row = wm + i * 16 + cl;
        int kb = ((g << 4) + (ks << 6)) ^ ((row & 7) << 4);
        af[i] = *(const bf16x8*)((const char*)As[buf] + row * 128 + kb);
      }
#pragma unroll
      for (int j = 0; j < 4; ++j) {
        int row = wn + j * 16 + cl;
        int kb = ((g << 4) + (ks << 6)) ^ ((row & 7) << 4);
        bfr[j] = *(const bf16x8*)((const char*)Bs[buf] + row * 128 + kb);
      }
#pragma unroll
      for (int i = 0; i < 4; ++i)
#pragma unroll
        for (int j = 0; j < 4; ++j)
          acc[i][j] = __builtin_amdgcn_mfma_f32_16x16x32_bf16(af[i], bfr[j], acc[i][j], 0, 0, 0);
    }
    asm volatile("s_waitcnt vmcnt(0)" ::: "memory");
    __syncthreads();
    buf ^= 1;
  }
#pragma unroll
  for (int i = 0; i < 4; ++i)
#pragma unroll
    for (int j = 0; j < 4; ++j)
#pragma unroll
      for (int r = 0; r < 4; ++r) {
        int row = m0 + wm + i * 16 + (g << 2) + r;
        int col = n0 + wn + j * 16 + cl;
        float v = acc[i][j][r];
        if (OUTF32)
          ((float*)Cout)[(size_t)row * N + col] = v;
        else
          ((unsigned short*)Cout)[(size_t)row * N + col] = f2bf(v);
      }
}

// ---------------- fused RoPE (Q,K in place) + V transpose ----------------
// Q scale folds attn_scale * hd^-0.5 * log2(e) -> softmax runs in exp2 domain.
__global__ void k_ropevt(unsigned short* __restrict__ qkv, const float* __restrict__ scale_p,
                         unsigned short* __restrict__ vt) {
  __shared__ unsigned short tl[64][80];
  if (blockIdx.x < 2560) {
    int idx = blockIdx.x * 256 + threadIdx.x;  // 2048 * 320 total
    int l = idx / 320;
    int u = idx - l * 320;
    int h = u >> 3;           // 0..39 (0-31 Q heads, 32-39 K heads)
    int i4 = (u & 7) << 2;    // 0,4,...,28
    int colbase = (h < 32) ? (h << 6) : (2048 + ((h - 32) << 6));
    unsigned short* p = qkv + (size_t)l * 3072 + colbase + i4;
    float sc = (h < 32) ? (scale_p[0] * 0.125f * 1.4426950408889634f) : 1.0f;
    ushort4 a = *(const ushort4*)p;
    ushort4 b = *(const ushort4*)(p + 32);
    unsigned short av[4] = {a.x, a.y, a.z, a.w};
    unsigned short bv[4] = {b.x, b.y, b.z, b.w};
    unsigned short r1[4], r2[4];
#pragma unroll
    for (int j = 0; j < 4; ++j) {
      int i = i4 + j;
      float invf = __expf(-(float)i * 0.2878231366242557f);  // ln(10000)/32
      float ang = (float)l * invf;
      float cs = cosf(ang), sn = sinf(ang);
      float x1 = bf2f(av[j]), x2 = bf2f(bv[j]);
      r1[j] = f2bf((x1 * cs - x2 * sn) * sc);
      r2[j] = f2bf((x1 * sn + x2 * cs) * sc);
    }
    ushort4 oa = {r1[0], r1[1], r1[2], r1[3]};
    ushort4 ob = {r2[0], r2[1], r2[2], r2[3]};
    *(ushort4*)p = oa;
    *(ushort4*)(p + 32) = ob;
  } else {
    const int tid = threadIdx.x;
    const int bb = blockIdx.x - 2560;
    const int hk = bb >> 5, lt = bb & 31;
    const int l0 = lt << 6;
#pragma unroll
    for (int it = 0; it < 2; ++it) {
      int cc = tid + it * 256;
      int lr = cc >> 3, d0 = (cc & 7) << 3;
      uint4 v = *(const uint4*)(qkv + (size_t)(l0 + lr) * 3072 + 2560 + hk * 64 + d0);
      *(uint4*)&tl[lr][d0] = v;
    }
    __syncthreads();
#pragma unroll
    for (int it = 0; it < 2; ++it) {
      int cc = tid + it * 256;
      int dr = cc >> 3, le = (cc & 7) << 3;
      unsigned short tmp[8] __attribute__((aligned(16)));
#pragma unroll
      for (int j = 0; j < 8; ++j) tmp[j] = tl[le + j][dr];
      *(uint4*)(vt + (size_t)(hk * 64 + dr) * 2048 + l0 + le) = *(const uint4*)tmp;
    }
  }
}

// ---------------- Flash attention: single-wave blocks, zero barriers ----------------
// Block = one wave = (head h, q-block qb, quarter): 16 q rows. K staged wave-private in
// LDS (single buffer, 8KB); V read directly from global VT (L2-resident); P via 2KB LDS.
// Pipeline per iter: V(i) loads -> vmcnt(8) [K(i) landed, V(i) in flight] -> QK(i) ->
// lgkmcnt(0) -> stage K(i+1) -> softmax(i) -> PV(i) [consumes V(i), K(i+1) stays in flight].
__global__ __launch_bounds__(64, 4) void k_attn(const unsigned short* __restrict__ qkv,
                                                const unsigned short* __restrict__ vt,
                                                unsigned short* __restrict__ ao) {
  __shared__ unsigned short Ks[64 * 64];   // 8KB [kv][d], XOR-swizzled rows
  __shared__ unsigned short Ps[16 * 64];   // 2KB wave-private P
  const int lane = threadIdx.x;
  const int g = lane >> 4, cl = lane & 15;
  const int h = blockIdx.x & 31;
  const int rest = blockIdx.x >> 5;        // 0..127
  const int qb = 31 - (rest >> 2);         // longest-first
  const int quarter = rest & 3;
  const int q0 = (qb << 6) + (quarter << 4);
  const int hk = h >> 2;
  const int qg = q0 + cl;

  const unsigned short* qptr = qkv + (size_t)qg * 3072 + h * 64 + g * 8;
  const unsigned short* kbase = qkv + 2048 + hk * 64;
  const unsigned short* vbase = vt + (size_t)hk * 64 * 2048;
  char* myP = (char*)Ps;

  auto stageK = [&](int ck) {
    const int kv0 = ck << 6;
#pragma unroll
    for (int it = 0; it < 8; ++it) {
      int cc = lane + it * 64;  // 512 chunks of 16B = 8KB
      int row = cc >> 3, kb = (cc & 7) << 4;
      const char* src = (const char*)(kbase + (size_t)(kv0 + row) * 3072) + (kb ^ ((row & 7) << 4));
      gload16(src, (char*)Ks + cc * 16);
    }
  };

  stageK(0);
  bf16x8 qf0 = *(const bf16x8*)qptr;
  bf16x8 qf1 = *(const bf16x8*)(qptr + 32);
  asm volatile("s_waitcnt vmcnt(0)" ::: "memory");  // qf + K(0) landed (once per block)

  float m_run = -3e38f, l_run = 0.0f;
  f32x4 acc[4] = {};

  for (int i = 0; i <= qb; ++i) {
    const int kv0 = i << 6;

    // ---- V(i): 8 direct global loads (L2-hot VT), consumed at PV ----
    bf16x8 vfr[2][4];
#pragma unroll
    for (int ks = 0; ks < 2; ++ks)
#pragma unroll
      for (int t = 0; t < 4; ++t)
        vfr[ks][t] = *(const bf16x8*)(vbase + (size_t)(t * 16 + cl) * 2048 + kv0 + ks * 32 + g * 8);

    // ---- K(i) guaranteed landed: V(i)'s 8 loads are the only newer ops ----
    asm volatile("s_waitcnt vmcnt(8)" ::: "memory");

    // ---- QK(i) from LDS ----
    float svP[4][4];
    __builtin_amdgcn_s_setprio(1);
#pragma unroll
    for (int t = 0; t < 4; ++t) {
      f32x4 st = {};
#pragma unroll
      for (int ks = 0; ks < 2; ++ks) {
        int row = t * 16 + cl;
        int kb = ((g << 4) + (ks << 6)) ^ ((row & 7) << 4);
        bf16x8 kf = *(const bf16x8*)((const char*)Ks + row * 128 + kb);
        st = __builtin_amdgcn_mfma_f32_16x16x32_bf16(kf, ks ? qf1 : qf0, st, 0, 0, 0);
      }
#pragma unroll
      for (int r = 0; r < 4; ++r) svP[t][r] = st[r];
    }
    __builtin_amdgcn_s_setprio(0);

    // ---- all K ds_reads done -> safe to overwrite Ks with K(i+1) ----
    asm volatile("s_waitcnt lgkmcnt(0)" ::: "memory");
    if (i < qb) stageK(i + 1);  // stays in flight through PV; drained next iter

    // ---- softmax(i), exp2 domain, defer-max ----
    if (i == qb) {
#pragma unroll
      for (int t = 0; t < 4; ++t)
#pragma unroll
        for (int r = 0; r < 4; ++r) {
          int kvg = kv0 + t * 16 + (g << 2) + r;
          if (kvg > qg) svP[t][r] = -1e9f;
        }
    }
    float pm[4];
#pragma unroll
    for (int t = 0; t < 4; ++t)
      pm[t] = fmaxf(fmaxf(svP[t][0], svP[t][1]), fmaxf(svP[t][2], svP[t][3]));
    float pmax = fmaxf(fmaxf(pm[0], pm[1]), fmaxf(pm[2], pm[3]));
    pmax = fmaxf(pmax, __shfl_xor(pmax, 16));
    pmax = fmaxf(pmax, __shfl_xor(pmax, 32));
    if (!__all(pmax - m_run <= 8.0f)) {
      float m_new = fmaxf(m_run, pmax);
      float fac = __builtin_exp2f(m_run - m_new);
      float fr[4];
#pragma unroll
      for (int r = 0; r < 4; ++r) fr[r] = __shfl(fac, (g << 2) + r);
#pragma unroll
      for (int t = 0; t < 4; ++t) {
        acc[t][0] *= fr[0]; acc[t][1] *= fr[1]; acc[t][2] *= fr[2]; acc[t][3] *= fr[3];
      }
      l_run *= fac;
      m_run = m_new;
    }
    float ps[4];
#pragma unroll
    for (int t = 0; t < 4; ++t) {
      float e0 = __builtin_exp2f(svP[t][0] - m_run);
      float e1 = __builtin_exp2f(svP[t][1] - m_run);
      float e2 = __builtin_exp2f(svP[t][2] - m_run);
      float e3 = __builtin_exp2f(svP[t][3] - m_run);
      ps[t] = (e0 + e1) + (e2 + e3);
      uint32_t d0, d1;
      asm("v_cvt_pk_bf16_f32 %0, %1, %2" : "=v"(d0) : "v"(e0), "v"(e1));
      asm("v_cvt_pk_bf16_f32 %0, %1, %2" : "=v"(d1) : "v"(e2), "v"(e3));
      uint2 dd; dd.x = d0; dd.y = d1;
      int kb = ((t << 5) + (g << 3)) ^ ((cl & 7) << 4);
      *(uint2*)(myP + cl * 128 + kb) = dd;
    }
    float psum = (ps[0] + ps[1]) + (ps[2] + ps[3]);
    psum += __shfl_xor(psum, 16);
    psum += __shfl_xor(psum, 32);
    l_run += psum;

    // ---- PV(i): P from LDS, V from registers ----
    __builtin_amdgcn_s_setprio(1);
#pragma unroll
    for (int ks = 0; ks < 2; ++ks) {
      int kbp = ((g << 4) + (ks << 6)) ^ ((cl & 7) << 4);
      bf16x8 pf = *(const bf16x8*)(myP + cl * 128 + kbp);
#pragma unroll
      for (int t = 0; t < 4; ++t)
        acc[t] = __builtin_amdgcn_mfma_f32_16x16x32_bf16(pf, vfr[ks][t], acc[t], 0, 0, 0);
    }
    __builtin_amdgcn_s_setprio(0);
  }

  float li[4];
#pragma unroll
  for (int r = 0; r < 4; ++r) li[r] = 1.0f / __shfl(l_run, (g << 2) + r);
#pragma unroll
  for (int t = 0; t < 4; ++t)
#pragma unroll
    for (int r = 0; r < 4; ++r) {
      int row = q0 + (g << 2) + r;
      int col = h * 64 + t * 16 + cl;
      ao[(size_t)row * 2048 + col] = f2bf(acc[t][r] * li[r]);
    }
}

extern "C" void kernel_launch(void* const* d_in, const int* in_sizes, int n_in,
                              void* d_out, int out_size, void* d_ws, size_t ws_size,
                              hipStream_t stream) {
  (void)in_sizes; (void)n_in; (void)out_size; (void)ws_size;
  const float* x  = (const float*)d_in[0];
  const float* sc = (const float*)d_in[1];
  // d_in[2] = mask (causal, applied analytically)
  const float* Wq = (const float*)d_in[3];
  const float* Wk = (const float*)d_in[4];
  const float* Wv = (const float*)d_in[5];
  const float* Wo = (const float*)d_in[6];
  float* out = (float*)d_out;
  char* ws = (char*)d_ws;
  unsigned short* xb   = (unsigned short*)(ws);              // 8 MB
  unsigned short* Wcat = (unsigned short*)(ws + 8388608);    // 12 MB  [3072][2048]
  unsigned short* Wob  = (unsigned short*)(ws + 20971520);   // 8 MB
  unsigned short* QKV  = (unsigned short*)(ws + 29360128);   // 12 MB  [2048][3072]
  unsigned short* VT   = (unsigned short*)(ws + 41943040);   // 2 MB   [8][64][2048]
  unsigned short* AO   = (unsigned short*)(ws + 44040192);   // 8 MB   [2048][2048]

  k_cvt_all<<<14336, 256, 0, stream>>>(x, Wq, Wk, Wv, Wo, xb, Wcat, Wob);
  k_gemm<0><<<384, 256, 0, stream>>>(xb, Wcat, QKV, 2048, 3072, 2048);
  k_ropevt<<<2816, 256, 0, stream>>>(QKV, sc, VT);
  k_attn<<<4096, 64, 0, stream>>>(QKV, VT, AO);
  k_gemm<1><<<256, 256, 0, stream>>>(AO, Wob, out, 2048, 2048, 2048);
}

// Round 10
// 125.987 us; speedup vs baseline: 1.7337x; 1.7337x over previous
//
#include <hip/hip_runtime.h>
#include <stdint.h>

typedef short bf16x8 __attribute__((ext_vector_type(8)));
typedef float f32x4 __attribute__((ext_vector_type(4)));

__device__ __forceinline__ unsigned short f2bf(float f) {
  uint32_t u = __float_as_uint(f);
  u = (u + 0x7FFFu + ((u >> 16) & 1u)) >> 16;
  return (unsigned short)u;
}
__device__ __forceinline__ float bf2f(unsigned short h) {
  return __uint_as_float(((uint32_t)h) << 16);
}

__device__ __forceinline__ void gload16(const void* g, void* lds) {
  const __attribute__((address_space(1))) char* gp =
      (const __attribute__((address_space(1))) char*)(uintptr_t)g;
  __attribute__((address_space(3))) char* sp =
      (__attribute__((address_space(3))) char*)(uint32_t)(uintptr_t)lds;
  __builtin_amdgcn_global_load_lds(gp, sp, 16, 0, 0);
}

// ---------------- fused fp32 -> bf16 converts (all 5 tensors, one dispatch) ----------------
__global__ void k_cvt_all(const float* __restrict__ x, const float* __restrict__ Wq,
                          const float* __restrict__ Wk, const float* __restrict__ Wv,
                          const float* __restrict__ Wo, unsigned short* __restrict__ xb,
                          unsigned short* __restrict__ Wcat, unsigned short* __restrict__ Wob) {
  int b = blockIdx.x;
  const float* src;
  unsigned short* dst;
  int off;
  if (b < 4096)       { src = x;  dst = xb;                  off = b; }
  else if (b < 8192)  { src = Wq; dst = Wcat;                off = b - 4096; }
  else if (b < 9216)  { src = Wk; dst = Wcat + 2048 * 2048;  off = b - 8192; }
  else if (b < 10240) { src = Wv; dst = Wcat + 2560 * 2048;  off = b - 9216; }
  else                { src = Wo; dst = Wob;                  off = b - 10240; }
  int i = off * 256 + threadIdx.x;
  float4 v = ((const float4*)src)[i];
  ushort4 o;
  o.x = f2bf(v.x); o.y = f2bf(v.y); o.z = f2bf(v.z); o.w = f2bf(v.w);
  ((ushort4*)dst)[i] = o;
}

// ---------------- bf16 GEMM, double-buffered: C[m][n] = sum_k A[m][k]*B[n][k] --------------
// ROPE=1 (gemm0): epilogue applies half-split RoPE in fp32 to Q (cols<2048, * scale*log2e)
// and K (2048<=col<2560); V region passthrough. Pair (t1,t2) = (acc[i][j], acc[i][j+2]).
template <int OUTF32, int ROPE>
__global__ __launch_bounds__(256) void k_gemm(const unsigned short* __restrict__ A,
                                              const unsigned short* __restrict__ B,
                                              void* __restrict__ Cout,
                                              int M, int N, int K,
                                              const float* __restrict__ scale_p) {
  __shared__ unsigned short As[2][128 * 64];
  __shared__ unsigned short Bs[2][128 * 64];
  const int tid = threadIdx.x;
  const int w = tid >> 6, lane = tid & 63;
  const int g = lane >> 4, cl = lane & 15;
  const int nTn = N >> 7;
  // XCD-aware bijective swizzle (gridDim.x % 8 == 0 for both call sites)
  const int per = gridDim.x >> 3;
  const int bid = (blockIdx.x & 7) * per + (blockIdx.x >> 3);
  const int tm = bid / nTn, tn = bid % nTn;
  const int m0 = tm << 7, n0 = tn << 7;
  const int wm = (w >> 1) << 6, wn = (w & 1) << 6;
  f32x4 acc[4][4] = {};

  auto stage = [&](int kt, int b) {
#pragma unroll
    for (int it = 0; it < 8; ++it) {
      int cc = tid + it * 256;          // 2048 16B chunks (As 1024 + Bs 1024)
      int half = cc >> 10;
      int c3 = cc & 1023;
      int row = c3 >> 3, kb = (c3 & 7) << 4;
      const unsigned short* base = half ? (B + (size_t)(n0 + row) * K + kt)
                                        : (A + (size_t)(m0 + row) * K + kt);
      const char* src = (const char*)base + (kb ^ ((row & 7) << 4));
      char* dstl = (char*)(half ? Bs[b] : As[b]) + c3 * 16;
      gload16(src, dstl);
    }
  };

  stage(0, 0);
  asm volatile("s_waitcnt vmcnt(0)" ::: "memory");
  __syncthreads();
  int buf = 0;

  for (int kt = 0; kt < K; kt += 64) {
    if (kt + 64 < K) stage(kt + 64, buf ^ 1);  // prefetch next K-tile, lands during compute
#pragma unroll
    for (int ks = 0; ks < 2; ++ks) {
      bf16x8 af[4], bfr[4];
#pragma unroll
      for (int i = 0; i < 4; ++i) {
        int row = wm + i * 16 + cl;
        int kb = ((g << 4) + (ks << 6)) ^ ((row & 7) << 4);
        af[i] = *(const bf16x8*)((const char*)As[buf] + row * 128 + kb);
      }
#pragma unroll
      for (int j = 0; j < 4; ++j) {
        int row = wn + j * 16 + cl;
        int kb = ((g << 4) + (ks << 6)) ^ ((row & 7) << 4);
        bfr[j] = *(const bf16x8*)((const char*)Bs[buf] + row * 128 + kb);
      }
#pragma unroll
      for (int i = 0; i < 4; ++i)
#pragma unroll
        for (int j = 0; j < 4; ++j)
          acc[i][j] = __builtin_amdgcn_mfma_f32_16x16x32_bf16(af[i], bfr[j], acc[i][j], 0, 0, 0);
    }
    asm volatile("s_waitcnt vmcnt(0)" ::: "memory");
    __syncthreads();
    buf ^= 1;
  }

  if (ROPE && n0 < 2560) {  // tile-uniform region: Q (<2048) or K (<2560)
    float s0v = scale_p[0] * 0.125f * 1.4426950408889634f;  // fold log2e: softmax in exp2
    float sc = (n0 < 2048) ? s0v : 1.0f;
    float invf[2];
#pragma unroll
    for (int j = 0; j < 2; ++j)
      invf[j] = __expf(-(float)(j * 16 + cl) * 0.2878231366242557f);  // ln(10000)/32
#pragma unroll
    for (int i = 0; i < 4; ++i)
#pragma unroll
      for (int r = 0; r < 4; ++r) {
        float pos = (float)(m0 + wm + i * 16 + (g << 2) + r);
#pragma unroll
        for (int j = 0; j < 2; ++j) {
          float ang = pos * invf[j];
          float sn, cs;
          __sincosf(ang, &sn, &cs);
          float t1 = acc[i][j][r], t2 = acc[i][j + 2][r];
          acc[i][j][r] = (t1 * cs - t2 * sn) * sc;
          acc[i][j + 2][r] = (t1 * sn + t2 * cs) * sc;
        }
      }
  }

#pragma unroll
  for (int i = 0; i < 4; ++i)
#pragma unroll
    for (int j = 0; j < 4; ++j)
#pragma unroll
      for (int r = 0; r < 4; ++r) {
        int row = m0 + wm + i * 16 + (g << 2) + r;
        int col = n0 + wn + j * 16 + cl;
        float v = acc[i][j][r];
        if (OUTF32)
          ((float*)Cout)[(size_t)row * N + col] = v;
        else
          ((unsigned short*)Cout)[(size_t)row * N + col] = f2bf(v);
      }
}

// ---------------- V transpose: VT[hk][d][l] from QKV V section ----------------
__global__ void k_vt(const unsigned short* __restrict__ qkv, unsigned short* __restrict__ vt) {
  __shared__ unsigned short tl[64][80];
  const int tid = threadIdx.x;
  const int hk = blockIdx.x >> 5, lt = blockIdx.x & 31;
  const int l0 = lt << 6;
#pragma unroll
  for (int it = 0; it < 2; ++it) {
    int cc = tid + it * 256;
    int lr = cc >> 3, d0 = (cc & 7) << 3;
    uint4 v = *(const uint4*)(qkv + (size_t)(l0 + lr) * 3072 + 2560 + hk * 64 + d0);
    *(uint4*)&tl[lr][d0] = v;
  }
  __syncthreads();
#pragma unroll
  for (int it = 0; it < 2; ++it) {
    int cc = tid + it * 256;
    int dr = cc >> 3, le = (cc & 7) << 3;
    unsigned short tmp[8] __attribute__((aligned(16)));
#pragma unroll
    for (int j = 0; j < 8; ++j) tmp[j] = tl[le + j][dr];
    *(uint4*)(vt + (size_t)(hk * 64 + dr) * 2048 + l0 + le) = *(const uint4*)tmp;
  }
}

// ---------------- Flash attention: R8 engine, 40KB LDS (K2+V2+P) -> 4 blocks/CU ---------
// Block = (head h, 64 q rows), 4 waves x 16 q. S^T = mfma(K,Q): stats lane-local at q=cl.
// Per iter i: stageK(i+2)|stageV(i+1) at top -> QK(i+1) -> SM(i) -> PV(i) -> vmcnt(0)+bar.
__global__ __launch_bounds__(256) void k_attn(const unsigned short* __restrict__ qkv,
                                              const unsigned short* __restrict__ vt,
                                              unsigned short* __restrict__ ao) {
  __shared__ unsigned short Ks[2][64 * 64];
  __shared__ unsigned short Vs[2][64 * 64];  // VT chunk: [d][kv]
  __shared__ unsigned short Ps[4 * 16 * 64];
  const int tid = threadIdx.x;
  const int w = tid >> 6, lane = tid & 63;
  const int g = lane >> 4, cl = lane & 15;
  const int h = blockIdx.x & 31;
  const int qb = 31 - (blockIdx.x >> 5);  // longest-first
  const int q0 = qb << 6;
  const int hk = h >> 2;
  const int qg = q0 + w * 16 + cl;

  const unsigned short* qptr = qkv + (size_t)qg * 3072 + h * 64 + g * 8;
  bf16x8 qf0 = *(const bf16x8*)qptr;
  bf16x8 qf1 = *(const bf16x8*)(qptr + 32);

  float m_run = -3e38f, l_run = 0.0f;
  f32x4 acc[4] = {};

  const unsigned short* kbase = qkv + 2048 + hk * 64;
  const unsigned short* vbase = vt + (size_t)hk * 64 * 2048;
  char* myP = (char*)Ps + w * 2048;

  auto stageK = [&](int ck, int b) {
    const int kv0 = ck << 6;
#pragma unroll
    for (int it = 0; it < 2; ++it) {
      int cc = tid + it * 256;  // 512 chunks of 16B
      int row = cc >> 3, kb = (cc & 7) << 4;
      const char* src = (const char*)(kbase + (size_t)(kv0 + row) * 3072) + (kb ^ ((row & 7) << 4));
      gload16(src, (char*)Ks[b] + cc * 16);
    }
  };
  auto stageV = [&](int ck, int b) {
    const int kv0 = ck << 6;
#pragma unroll
    for (int it = 0; it < 2; ++it) {
      int cc = tid + it * 256;
      int row = cc >> 3, kb = (cc & 7) << 4;
      const char* src = (const char*)(vbase + (size_t)row * 2048 + kv0) + (kb ^ ((row & 7) << 4));
      gload16(src, (char*)Vs[b] + cc * 16);
    }
  };

  // prologue: K0,V0 (+K1) staged; QK(0) computed
  stageK(0, 0); stageV(0, 0);
  if (qb >= 1) stageK(1, 1);
  asm volatile("s_waitcnt vmcnt(0)" ::: "memory");
  __syncthreads();

  float svP[4][4];
  {
    const char* Kc = (const char*)Ks[0];
    __builtin_amdgcn_s_setprio(1);
#pragma unroll
    for (int t = 0; t < 4; ++t) {
      f32x4 st = {};
#pragma unroll
      for (int ks = 0; ks < 2; ++ks) {
        int row = t * 16 + cl;
        int kb = ((g << 4) + (ks << 6)) ^ ((row & 7) << 4);
        bf16x8 kf = *(const bf16x8*)(Kc + row * 128 + kb);
        st = __builtin_amdgcn_mfma_f32_16x16x32_bf16(kf, ks ? qf1 : qf0, st, 0, 0, 0);
      }
#pragma unroll
      for (int r = 0; r < 4; ++r) svP[t][r] = st[r];
    }
    __builtin_amdgcn_s_setprio(0);
  }
  __syncthreads();  // all waves done reading Ks[0] before iter-0 stages K(2) into it

  for (int i = 0; i <= qb; ++i) {
    if (i + 2 <= qb) stageK(i + 2, i & 1);            // write Ks[i&1]; QK(i+1) reads Ks[(i+1)&1]
    if (i + 1 <= qb) stageV(i + 1, (i + 1) & 1);      // write Vs[(i+1)&1]; PV(i) reads Vs[i&1]

    // QK for tile i+1 (K(i+1) staged >=1 iter ago, landed by prior vmcnt(0))
    float svN[4][4];
    if (i < qb) {
      const char* Kc = (const char*)Ks[(i + 1) & 1];
      __builtin_amdgcn_s_setprio(1);
#pragma unroll
      for (int t = 0; t < 4; ++t) {
        f32x4 st = {};
#pragma unroll
        for (int ks = 0; ks < 2; ++ks) {
          int row = t * 16 + cl;
          int kb = ((g << 4) + (ks << 6)) ^ ((row & 7) << 4);
          bf16x8 kf = *(const bf16x8*)(Kc + row * 128 + kb);
          st = __builtin_amdgcn_mfma_f32_16x16x32_bf16(kf, ks ? qf1 : qf0, st, 0, 0, 0);
        }
#pragma unroll
        for (int r = 0; r < 4; ++r) svN[t][r] = st[r];
      }
      __builtin_amdgcn_s_setprio(0);
    }

    // softmax on tile i (svP), exp2 domain, defer-max
    if (i == qb) {  // diagonal: causal mask
      const int kv0 = i << 6;
#pragma unroll
      for (int t = 0; t < 4; ++t)
#pragma unroll
        for (int r = 0; r < 4; ++r) {
          int kvg = kv0 + t * 16 + (g << 2) + r;
          if (kvg > qg) svP[t][r] = -1e9f;
        }
    }
    float pm[4];
#pragma unroll
    for (int t = 0; t < 4; ++t)
      pm[t] = fmaxf(fmaxf(svP[t][0], svP[t][1]), fmaxf(svP[t][2], svP[t][3]));
    float pmax = fmaxf(fmaxf(pm[0], pm[1]), fmaxf(pm[2], pm[3]));
    pmax = fmaxf(pmax, __shfl_xor(pmax, 16));
    pmax = fmaxf(pmax, __shfl_xor(pmax, 32));
    if (!__all(pmax - m_run <= 8.0f)) {
      float m_new = fmaxf(m_run, pmax);
      float fac = __builtin_exp2f(m_run - m_new);
      float fr[4];
#pragma unroll
      for (int r = 0; r < 4; ++r) fr[r] = __shfl(fac, (g << 2) + r);
#pragma unroll
      for (int t = 0; t < 4; ++t) {
        acc[t][0] *= fr[0]; acc[t][1] *= fr[1]; acc[t][2] *= fr[2]; acc[t][3] *= fr[3];
      }
      l_run *= fac;
      m_run = m_new;
    }
    float ps[4];
#pragma unroll
    for (int t = 0; t < 4; ++t) {
      float e0 = __builtin_exp2f(svP[t][0] - m_run);
      float e1 = __builtin_exp2f(svP[t][1] - m_run);
      float e2 = __builtin_exp2f(svP[t][2] - m_run);
      float e3 = __builtin_exp2f(svP[t][3] - m_run);
      ps[t] = (e0 + e1) + (e2 + e3);
      uint32_t d0, d1;
      asm("v_cvt_pk_bf16_f32 %0, %1, %2" : "=v"(d0) : "v"(e0), "v"(e1));
      asm("v_cvt_pk_bf16_f32 %0, %1, %2" : "=v"(d1) : "v"(e2), "v"(e3));
      uint2 dd; dd.x = d0; dd.y = d1;
      int kb = ((t << 5) + (g << 3)) ^ ((cl & 7) << 4);
      *(uint2*)(myP + cl * 128 + kb) = dd;
    }
    float psum = (ps[0] + ps[1]) + (ps[2] + ps[3]);
    psum += __shfl_xor(psum, 16);
    psum += __shfl_xor(psum, 32);
    l_run += psum;

    // PV for tile i
    {
      const char* Vc = (const char*)Vs[i & 1];
      __builtin_amdgcn_s_setprio(1);
#pragma unroll
      for (int ks = 0; ks < 2; ++ks) {
        int kbp = ((g << 4) + (ks << 6)) ^ ((cl & 7) << 4);
        bf16x8 pf = *(const bf16x8*)(myP + cl * 128 + kbp);
#pragma unroll
        for (int t = 0; t < 4; ++t) {
          int row = t * 16 + cl;
          int kbv = ((g << 4) + (ks << 6)) ^ ((row & 7) << 4);
          bf16x8 vf = *(const bf16x8*)(Vc + row * 128 + kbv);
          acc[t] = __builtin_amdgcn_mfma_f32_16x16x32_bf16(pf, vf, acc[t], 0, 0, 0);
        }
      }
      __builtin_amdgcn_s_setprio(0);
    }

    if (i < qb) {
      asm volatile("s_waitcnt vmcnt(0)" ::: "memory");  // K(i+2),V(i+1) landed
      __syncthreads();
#pragma unroll
      for (int t = 0; t < 4; ++t)
#pragma unroll
        for (int r = 0; r < 4; ++r) svP[t][r] = svN[t][r];
    }
  }

  float li[4];
#pragma unroll
  for (int r = 0; r < 4; ++r) li[r] = 1.0f / __shfl(l_run, (g << 2) + r);
#pragma unroll
  for (int t = 0; t < 4; ++t)
#pragma unroll
    for (int r = 0; r < 4; ++r) {
      int row = q0 + w * 16 + (g << 2) + r;
      int col = h * 64 + t * 16 + cl;
      ao[(size_t)row * 2048 + col] = f2bf(acc[t][r] * li[r]);
    }
}

extern "C" void kernel_launch(void* const* d_in, const int* in_sizes, int n_in,
                              void* d_out, int out_size, void* d_ws, size_t ws_size,
                              hipStream_t stream) {
  (void)in_sizes; (void)n_in; (void)out_size; (void)ws_size;
  const float* x  = (const float*)d_in[0];
  const float* sc = (const float*)d_in[1];
  // d_in[2] = mask (causal, applied analytically)
  const float* Wq = (const float*)d_in[3];
  const float* Wk = (const float*)d_in[4];
  const float* Wv = (const float*)d_in[5];
  const float* Wo = (const float*)d_in[6];
  float* out = (float*)d_out;
  char* ws = (char*)d_ws;
  unsigned short* xb   = (unsigned short*)(ws);              // 8 MB
  unsigned short* Wcat = (unsigned short*)(ws + 8388608);    // 12 MB  [3072][2048]
  unsigned short* Wob  = (unsigned short*)(ws + 20971520);   // 8 MB
  unsigned short* QKV  = (unsigned short*)(ws + 29360128);   // 12 MB  [2048][3072]
  unsigned short* VT   = (unsigned short*)(ws + 41943040);   // 2 MB   [8][64][2048]
  unsigned short* AO   = (unsigned short*)(ws + 44040192);   // 8 MB   [2048][2048]

  k_cvt_all<<<14336, 256, 0, stream>>>(x, Wq, Wk, Wv, Wo, xb, Wcat, Wob);
  k_gemm<0, 1><<<384, 256, 0, stream>>>(xb, Wcat, QKV, 2048, 3072, 2048, sc);  // +RoPE epilogue
  k_vt<<<256, 256, 0, stream>>>(QKV, VT);
  k_attn<<<1024, 256, 0, stream>>>(QKV, VT, AO);
  k_gemm<1, 0><<<256, 256, 0, stream>>>(AO, Wob, out, 2048, 2048, 2048, nullptr);
}